// Round 7
// baseline (306.745 us; speedup 1.0000x reference)
//
#include <hip/hip_runtime.h>
#include <stdint.h>

// ---------------------------------------------------------------------------
// GPT-2 attention block: qkv = X@W + b; causal MHA; outputs attn_out + present
// B=4 S=2048 D=1024 H=16 Dh=64.  bf16 MFMA path.
// R11: R10 + equal-sum panel pairing.  All 512 blocks are CO-RESIDENT
//     (2 blocks/CU): LPT order is irrelevant; the per-CU SUM of the two
//     resident blocks is what matters.  Under XCD round-robin, CU c hosts
//     blocks c and c+256 -> map blockIdx.y to panels {7,6,5,4,0,1,2,3} so
//     every pair sums to 36 double-tile-iters (R10's 7-y gave 48 vs 24).
// ---------------------------------------------------------------------------

#define B_SZ    4
#define S_LEN   2048
#define D_MODEL 1024
#define N3      3072
#define H_NUM   16
#define DH      64
#define M_TOT   8192   // B*S

typedef __attribute__((ext_vector_type(8))) short short8;   // 8 bf16 (4 VGPRs)
typedef __attribute__((ext_vector_type(4))) short bf16x4;   // 4 bf16 (2 VGPRs)
typedef __attribute__((ext_vector_type(4))) float f32x4;    // MFMA C/D

#define LOG2E      1.4426950408889634f
#define SCL2E      0.18033688011112042f   /* 0.125 * log2(e) */
#define MASKB2     (-14426.9504f)         /* -10000 * log2(e) */

__device__ __forceinline__ unsigned short f2b(float f) {
  union { float f; unsigned int u; } x;
  x.f = f;
  unsigned int u = x.u;
  u += 0x7fffu + ((u >> 16) & 1u);   // round-to-nearest-even
  return (unsigned short)(u >> 16);
}

__device__ __forceinline__ unsigned int cvt_pk_bf16(float lo, float hi) {
  unsigned int r;
  asm("v_cvt_pk_bf16_f32 %0, %1, %2" : "=v"(r) : "v"(lo), "v"(hi));
  return r;
}

__device__ __forceinline__ float exp2_fast(float x) {
#if __has_builtin(__builtin_amdgcn_exp2f)
  return __builtin_amdgcn_exp2f(x);
#else
  return __expf(x * 0.6931471805599453f);
#endif
}

__device__ __forceinline__ f32x4 mfma16(bf16x4 a, bf16x4 b, f32x4 c) {
#if __has_builtin(__builtin_amdgcn_mfma_f32_16x16x16bf16_1k)
  return __builtin_amdgcn_mfma_f32_16x16x16bf16_1k(a, b, c, 0, 0, 0);
#else
  asm("v_mfma_f32_16x16x16_bf16 %0, %1, %2, %0" : "+v"(c) : "v"(a), "v"(b));
  return c;
#endif
}

// async global->LDS, 16B per lane. LDS dest = wave-uniform base + lane*16.
__device__ __forceinline__ void async16(const void* g, void* l) {
  __builtin_amdgcn_global_load_lds((const __attribute__((address_space(1))) void*)g,
                                   (__attribute__((address_space(3))) void*)l,
                                   16, 0, 0);
}

// ---------------- kernel 1: hidden_states fp32 -> bf16 ---------------------
__global__ void k_convert_x(const float* __restrict__ X, unsigned short* __restrict__ Xb) {
  const int i = (blockIdx.x * 256 + threadIdx.x) * 4;
  const float4 v = *(const float4*)(X + i);
  ushort4 o;
  o.x = f2b(v.x); o.y = f2b(v.y); o.z = f2b(v.z); o.w = f2b(v.w);
  *(ushort4*)(Xb + i) = o;
}

// ---------------- kernel 2: W [D,3D] fp32 -> W^T [3D,D] bf16 ----------------
__global__ void k_wt(const float* __restrict__ W, unsigned short* __restrict__ Wt) {
  __shared__ float tile[32][33];
  const int n0 = blockIdx.x * 32, k0 = blockIdx.y * 32;
  const int tx = threadIdx.x, ty = threadIdx.y;   // 32 x 8
  for (int i = 0; i < 32; i += 8)
    tile[ty + i][tx] = W[(size_t)(k0 + ty + i) * N3 + n0 + tx];
  __syncthreads();
  for (int i = 0; i < 32; i += 8)
    Wt[(size_t)(n0 + ty + i) * D_MODEL + k0 + tx] = f2b(tile[tx][ty + i]);
}

// ---------------- kernel 3: QKV GEMM (128x128 tile, BK=32) ------------------
// K-loop: exact R5 structure (m97-class).  Epilogue: per-wave LDS slab
// transpose -> coalesced 128B-row stores for Qb/Kb.
__global__ __launch_bounds__(256) void k_gemm_qkv(
    const unsigned short* __restrict__ Xb, const unsigned short* __restrict__ Wt,
    const float* __restrict__ bias,
    unsigned short* __restrict__ Qb, unsigned short* __restrict__ Kb,
    float* __restrict__ presK, float* __restrict__ presV) {
  __shared__ __align__(16) unsigned short SMEM[8192];   // 16 KB
  unsigned short* As = SMEM;          // [128*32]
  unsigned short* Bs = SMEM + 4096;   // [128*32]
  const int t = threadIdx.x;
  const int lane = t & 63, wave = t >> 6;
  const int g = lane >> 4, c = lane & 15;
  const int m0 = blockIdx.y * 128, n0 = blockIdx.x * 128;
  const int wm = (wave >> 1) * 64, wn = (wave & 1) * 64;

  const f32x4 zero = {0.f, 0.f, 0.f, 0.f};
  f32x4 acc[4][4];
  for (int i = 0; i < 4; ++i)
    for (int j = 0; j < 4; ++j) acc[i][j] = zero;

  const int row_a = t >> 2;          // 0..63
  const int col_a = (t & 3) * 8;     // bf16 elems
  const unsigned short* gA = Xb + (size_t)(m0 + row_a) * D_MODEL + col_a;
  const unsigned short* gB = Wt + (size_t)(n0 + row_a) * D_MODEL + col_a;
  const int wbase = wave * 1024;     // wave-uniform LDS byte base

  for (int k0 = 0; k0 < D_MODEL; k0 += 32) {
    __syncthreads();
    async16(gA + k0,                (char*)As + wbase);
    async16(gA + k0 + 64 * D_MODEL, (char*)As + 4096 + wbase);
    async16(gB + k0,                (char*)Bs + wbase);
    async16(gB + k0 + 64 * D_MODEL, (char*)Bs + 4096 + wbase);
    __syncthreads();

    short8 af[4], bf[4];
    for (int mi = 0; mi < 4; ++mi)
      af[mi] = *(const short8*)(As + (wm + mi * 16 + c) * 32 + g * 8);
    for (int ni = 0; ni < 4; ++ni)
      bf[ni] = *(const short8*)(Bs + (wn + ni * 16 + c) * 32 + g * 8);
    for (int mi = 0; mi < 4; ++mi)
      for (int ni = 0; ni < 4; ++ni)
        acc[mi][ni] = __builtin_amdgcn_mfma_f32_16x16x32_bf16(af[mi], bf[ni], acc[mi][ni], 0, 0, 0);
  }

  __syncthreads();                   // staging LDS reuse as epilogue slab

  // ---- epilogue ----
  // Per wave: one (sec,h); cols = wn + ni*16+c (dh = ni*16+c), rows = wm+mi*16+...
  // C/D layout: col=lane&15 (c), row=(lane>>4)*4+reg (g*4+r).
  const int sec = (n0 + wn) >> 10;            // 0=q 1=k 2=v (wave-uniform)
  const int h = ((n0 + wn) & 1023) >> 6;      // head (wave-uniform)
  unsigned short* slab = SMEM + wave * 1152;  // [16 rows][72 cols] bf16, per-wave
  float bv[4];
  for (int ni = 0; ni < 4; ++ni) bv[ni] = bias[n0 + wn + ni * 16 + c];

  for (int mi = 0; mi < 4; ++mi) {
    const int mrow = m0 + wm + mi * 16;

    if (sec != 2) {
      // bf16 path (Qb / Kb): slab transpose -> 128B coalesced rows
      for (int ni = 0; ni < 4; ++ni)
        for (int r = 0; r < 4; ++r)
          slab[(g * 4 + r) * 72 + ni * 16 + c] = f2b(acc[mi][ni][r] + bv[ni]);
      // same-wave DS ordering; compiler inserts lgkmcnt for the RAW dep
      const short8 w0 = *(const short8*)(slab + c * 72 + g * 16);
      const short8 w1 = *(const short8*)(slab + c * 72 + g * 16 + 8);
      const int srow = mrow + c;
      const int b = srow >> 11, s = srow & 2047;
      unsigned short* dst = (sec == 0 ? Qb : Kb) +
          ((size_t)((b * H_NUM + h) * S_LEN + s)) * DH + g * 16;
      *(short8*)(dst) = w0;
      *(short8*)(dst + 8) = w1;
    }
    if (sec >= 1) {
      // f32 path (presK / presV): direct 64B-segment stores (as R5)
      float* dstf = (sec == 1) ? presK : presV;
      for (int ni = 0; ni < 4; ++ni) {
        const int dh = ni * 16 + c;
        for (int r = 0; r < 4; ++r) {
          const int m = mrow + g * 4 + r;
          const int b = m >> 11, s = m & 2047;
          dstf[((size_t)((b * H_NUM + h) * S_LEN + s)) * DH + dh] =
              acc[mi][ni][r] + bv[ni];
        }
      }
    }
  }
}

// ---------------- kernel 3b: presV fp32 [bh,s,dh] -> Vt bf16 [bh,dh,s] ------
// Vt rows are PERMUTED within each 64-s group: element k stored at position
// p(k) with p[3:2]=k[5:4], p[5:4]=k[3:2], p[1:0]=k[1:0]  (involution), so
// k_flash fetches two ks-fragments per b128.
__global__ __launch_bounds__(256) void k_vt(const float* __restrict__ presV,
                                            unsigned short* __restrict__ Vt) {
  __shared__ unsigned short tile[64 * 72];
  const int t = threadIdx.x;
  const int bh = blockIdx.y;
  const int s0 = blockIdx.x * 64;
  const int row = t >> 2;            // s-row 0..63
  const int dh0 = (t & 3) * 16;
  const float* src = presV + ((size_t)bh * S_LEN + s0 + row) * DH + dh0;
  for (int i = 0; i < 4; ++i) {
    const float4 v = *(const float4*)(src + i * 4);
    const int dh = dh0 + i * 4;
    tile[(dh + 0) * 72 + row] = f2b(v.x);
    tile[(dh + 1) * 72 + row] = f2b(v.y);
    tile[(dh + 2) * 72 + row] = f2b(v.z);
    tile[(dh + 3) * 72 + row] = f2b(v.w);
  }
  __syncthreads();
  const int dh = t >> 2, p0 = (t & 3) * 16;
  unsigned short* dst = Vt + ((size_t)bh * DH + dh) * S_LEN + s0 + p0;
  short8 o0, o1;
  for (int i = 0; i < 8; ++i) {
    const int pa = p0 + i, pb = p0 + 8 + i;
    const int ka = (((pa >> 2) & 3) << 4) | (((pa >> 4) & 3) << 2) | (pa & 3);
    const int kb = (((pb >> 2) & 3) << 4) | (((pb >> 4) & 3) << 2) | (pb & 3);
    o0[i] = (short)tile[dh * 72 + ka];
    o1[i] = (short)tile[dh * 72 + kb];
  }
  *(short8*)(dst) = o0;
  *(short8*)(dst + 8) = o1;
}

// ---------------- kernel 4: causal flash attention --------------------------
// grid (64 bh, 8 panels); 512 thr = 8 waves x 32 q-rows (sets A/B) per wave.
// Panel map {7,6,5,4,0,1,2,3}: co-resident block pairs (c, c+256) sum to a
// constant 36 double-tile-iters -> no per-CU imbalance.
// Sequential per-set QK^T+softmax (reg pressure), SHARED V-frag for both PV
// steps.  Swapped QK^T, defer-max, cvt_pk, b128 V (permuted Vt), counted
// vmcnt(2) dbuf.  64-tile boundaries never split A/B.
#define PROC_SET(BQ, QR, NC, MI, LI, OA, PK)                                \
  {                                                                         \
    f32x4 sc[4];                                                            \
    _Pragma("unroll")                                                       \
    for (int ks = 0; ks < 4; ++ks) {                                        \
      f32x4 a = zero;                                                       \
      const int krow = ks * 16 + c;                                         \
      _Pragma("unroll")                                                     \
      for (int kc = 0; kc < 2; ++kc) {                                      \
        const short8 ak = *(const short8*)(ks_base + krow * 64 +            \
                                           (((kc * 4 + g) ^ kslot) * 8));   \
        a = __builtin_amdgcn_mfma_f32_16x16x32_bf16(ak, BQ[kc], a, 0, 0, 0);\
      }                                                                     \
      sc[ks] = a;                                                           \
    }                                                                       \
    float mx = -3.0e38f;                                                    \
    _Pragma("unroll")                                                       \
    for (int ks = 0; ks < 4; ++ks) {                                        \
      _Pragma("unroll")                                                     \
      for (int r = 0; r < 4; ++r) {                                         \
        float v = sc[ks][r] * SCL2E + amf[ks][r];                           \
        if (NC && (kb + ks * 16 + g * 4 + r > (QR))) v = MASKB2 + amf[ks][r];\
        sc[ks][r] = v;                                                      \
      }                                                                     \
      mx = fmaxf(mx, fmaxf(fmaxf(sc[ks][0], sc[ks][1]),                     \
                           fmaxf(sc[ks][2], sc[ks][3])));                   \
    }                                                                       \
    mx = fmaxf(mx, __shfl_xor(mx, 16));                                     \
    mx = fmaxf(mx, __shfl_xor(mx, 32));                                     \
    if (!__all(mx <= MI + 8.0f)) {                                          \
      const float mnew = fmaxf(MI, mx);                                     \
      const float alpha = exp2_fast(MI - mnew);                             \
      MI = mnew;                                                            \
      LI *= alpha;                                                          \
      _Pragma("unroll")                                                     \
      for (int dt = 0; dt < 4; ++dt) OA[dt] *= alpha;                       \
    }                                                                       \
    float rs = 0.f;                                                         \
    _Pragma("unroll")                                                       \
    for (int ks = 0; ks < 4; ++ks) {                                        \
      const float p0 = exp2_fast(sc[ks][0] - MI);                           \
      const float p1 = exp2_fast(sc[ks][1] - MI);                           \
      const float p2 = exp2_fast(sc[ks][2] - MI);                           \
      const float p3 = exp2_fast(sc[ks][3] - MI);                           \
      rs += (p0 + p1) + (p2 + p3);                                          \
      union { unsigned int u[2]; bf16x4 v4; } pu;                           \
      pu.u[0] = cvt_pk_bf16(p0, p1);                                        \
      pu.u[1] = cvt_pk_bf16(p2, p3);                                        \
      PK[ks] = pu.v4;                                                       \
    }                                                                       \
    rs += __shfl_xor(rs, 16);                                               \
    rs += __shfl_xor(rs, 32);                                               \
    LI += rs;                                                               \
  }

__global__ __launch_bounds__(512) void k_flash(
    const unsigned short* __restrict__ Qb, const unsigned short* __restrict__ Kb,
    const unsigned short* __restrict__ Vt, const float* __restrict__ mask,
    float* __restrict__ out) {
  __shared__ __align__(16) unsigned short Ks[2][64 * 64];  // [row][slot] swizzled
  __shared__ __align__(16) unsigned short Vs[2][64 * 64];  // [dh][slot]  swizzled
  __shared__ __align__(16) float Ams[S_LEN];               // (1-mask)*-1e4*log2e
  const int t = threadIdx.x;
  const int lane = t & 63, wave = t >> 6;
  const int g = lane >> 4, c = lane & 15;
  const int bh = blockIdx.x;               // bh FAST -> pair (c, c+256) differs
  const int b = bh >> 4, h = bh & 15;      //   only in panel -> equal-sum pairs
  // staging: thread -> (row 0..63, swizzled 16B chunk); swizzle folded into
  // the GLOBAL gather address, LDS side stays base+lane*16 (rigid).
  const int srow = t >> 3;
  const int schunk = (t & 7) ^ (srow & 7);
  const unsigned short* gK0 = Kb + ((size_t)bh * S_LEN + srow) * DH + schunk * 8;
  const unsigned short* gV0 = Vt + ((size_t)bh * DH + srow) * S_LEN + schunk * 8;
  const int kslot = c & 7;                 // frag-read slot xor term

  // exp2-domain additive mask bias, staged once (keeps inner loop VMEM = 2)
  {
    const float4 mv = *(const float4*)(mask + (size_t)b * S_LEN + t * 4);
    float4 o;
    o.x = (1.0f - mv.x) * MASKB2;
    o.y = (1.0f - mv.y) * MASKB2;
    o.z = (1.0f - mv.z) * MASKB2;
    o.w = (1.0f - mv.w) * MASKB2;
    *(float4*)(Ams + t * 4) = o;
  }

  const f32x4 zero = {0.f, 0.f, 0.f, 0.f};

  // equal-sum pairing: y 0..3 -> panels 7,6,5,4; y 4..7 -> panels 0,1,2,3
  const int y = (int)blockIdx.y;
  const int panel = (y < 4) ? (7 - y) : (y - 4);
  const int qb = panel * 256;              // this block's 256-row q panel
  const int qw = qb + wave * 32;           // this wave's 32 q rows (A:0-15 B:16-31)
  const int qrA = qw + c;                  // lane's q row, set A
  const int qrB = qw + 16 + c;             // lane's q row, set B

  // Q B-frags for both sets (x32 B-layout: n=c, k=g*8+j per 32-wide chunk)
  short8 bqA[2], bqB[2];
  {
    const size_t qoff = ((size_t)bh * S_LEN + qw) * DH;
#pragma unroll
    for (int kc = 0; kc < 2; ++kc) {
      bqA[kc] = *(const short8*)(Qb + qoff + (size_t)c * DH + kc * 32 + g * 8);
      bqB[kc] = *(const short8*)(Qb + qoff + (size_t)(c + 16) * DH + kc * 32 + g * 8);
    }
  }

  float m_iA = -1e30f, l_iA = 0.f, m_iB = -1e30f, l_iB = 0.f;
  f32x4 o_A[4], o_B[4];                    // o[dt][r] = O[q][d=16dt+4g+r]
#pragma unroll
  for (int dt = 0; dt < 4; ++dt) { o_A[dt] = zero; o_B[dt] = zero; }

  const int nt = (qb + 256) >> 6;
  // prologue: stage tile 0 into buffer 0
  async16(gK0, (char*)(&Ks[0][0]) + wave * 1024);
  async16(gV0, (char*)(&Vs[0][0]) + wave * 1024);

  for (int tt = 0; tt < nt; ++tt) {
    const int kb = tt << 6;
    const int cur = tt & 1;
    if (tt + 1 < nt) {                     // prefetch next tile, keep 2 in flight
      async16(gK0 + (size_t)(kb + 64) * DH, (char*)(&Ks[cur ^ 1][0]) + wave * 1024);
      async16(gV0 + (kb + 64),              (char*)(&Vs[cur ^ 1][0]) + wave * 1024);
      asm volatile("s_waitcnt vmcnt(2) lgkmcnt(0)" ::: "memory");
    } else {
      asm volatile("s_waitcnt vmcnt(0) lgkmcnt(0)" ::: "memory");
    }
    __builtin_amdgcn_s_barrier();          // tile kb fully staged (all waves)
    __builtin_amdgcn_sched_barrier(0);

    // A/B never straddle a 64-tile boundary -> one guard for both sets
    if (qw + 32 > kb) {
      const unsigned short* ks_base = &Ks[cur][0];
      const unsigned short* vs_base = &Vs[cur][0];

      // ---- additive mask (shared by both sets) ----
      float amf[4][4];
#pragma unroll
      for (int ks = 0; ks < 4; ++ks) {
        const float4 amv = *(const float4*)(Ams + kb + ks * 16 + g * 4);
        amf[ks][0] = amv.x; amf[ks][1] = amv.y;
        amf[ks][2] = amv.z; amf[ks][3] = amv.w;
      }
      const bool ncA = (kb + 63 > qw);
      const bool ncB = (kb + 63 > qw + 16);

      // ---- per-set QK^T + softmax + pack, SEQUENTIAL (reg pressure) ----
      bf16x4 pkA[4], pkB[4];
      PROC_SET(bqA, qrA, ncA, m_iA, l_iA, o_A, pkA)
      PROC_SET(bqB, qrB, ncB, m_iB, l_iB, o_B, pkB)

      // ---- O^T += V^T P^T, both sets share the V-frag (8 b128, 32 MFMA) ----
#pragma unroll
      for (int dt = 0; dt < 4; ++dt) {
        const int vrow = dt * 16 + c;
#pragma unroll
        for (int jp = 0; jp < 2; ++jp) {
          union { short8 s8; bf16x4 h[2]; } vv;
          vv.s8 = *(const short8*)(vs_base + vrow * 64 + (((2 * g + jp) ^ kslot) * 8));
          o_A[dt] = mfma16(vv.h[0], pkA[2 * jp], o_A[dt]);
          o_A[dt] = mfma16(vv.h[1], pkA[2 * jp + 1], o_A[dt]);
          o_B[dt] = mfma16(vv.h[0], pkB[2 * jp], o_B[dt]);
          o_B[dt] = mfma16(vv.h[1], pkB[2 * jp + 1], o_B[dt]);
        }
      }
    }
    __builtin_amdgcn_sched_barrier(0);
    __builtin_amdgcn_s_barrier();          // all waves done reading buf[cur]
  }

  // ---- normalize + merge heads: O[q][d=16dt+4g+r], float4 stores ----
  {
    const float inv = 1.0f / l_iA;
    float* orow = out + ((size_t)(b * S_LEN + qrA)) * D_MODEL + h * DH;
#pragma unroll
    for (int dt = 0; dt < 4; ++dt) {
      float4 o;
      o.x = o_A[dt][0] * inv;
      o.y = o_A[dt][1] * inv;
      o.z = o_A[dt][2] * inv;
      o.w = o_A[dt][3] * inv;
      *(float4*)(orow + dt * 16 + g * 4) = o;
    }
  }
  {
    const float inv = 1.0f / l_iB;
    float* orow = out + ((size_t)(b * S_LEN + qrB)) * D_MODEL + h * DH;
#pragma unroll
    for (int dt = 0; dt < 4; ++dt) {
      float4 o;
      o.x = o_B[dt][0] * inv;
      o.y = o_B[dt][1] * inv;
      o.z = o_B[dt][2] * inv;
      o.w = o_B[dt][3] * inv;
      *(float4*)(orow + dt * 16 + g * 4) = o;
    }
  }
}

// ---------------------------------------------------------------------------
extern "C" void kernel_launch(void* const* d_in, const int* in_sizes, int n_in,
                              void* d_out, int out_size, void* d_ws, size_t ws_size,
                              hipStream_t stream) {
  const float* X    = (const float*)d_in[0];   // [4,2048,1024]
  const float* mask = (const float*)d_in[1];   // [4,2048]
  const float* W    = (const float*)d_in[2];   // [1024,3072]
  const float* bias = (const float*)d_in[3];   // [3072]

  float* out   = (float*)d_out;                         // attn_output [4,2048,1024]
  float* presK = out + (size_t)M_TOT * D_MODEL;         // present[0]  [4,16,2048,64]
  float* presV = presK + (size_t)M_TOT * D_MODEL;       // present[1]

  char* ws = (char*)d_ws;
  unsigned short* Xb = (unsigned short*)(ws);                    // 16 MB  X bf16 [8192,1024]
  unsigned short* Wt = (unsigned short*)(ws + 16777216);         //  6 MB  W^T bf16 [3072,1024]
  unsigned short* Qb = (unsigned short*)(ws + 23068672);         // 16 MB  Q bf16 [bh,2048,64]
  unsigned short* Kb = (unsigned short*)(ws + 39845888);         // 16 MB  K bf16 [bh,2048,64]
  unsigned short* Vt = (unsigned short*)(ws + 56623104);         // 16 MB  V^T bf16 [bh,64,2048] (row-permuted)

  k_convert_x<<<dim3(8192), dim3(256), 0, stream>>>(X, Xb);
  k_wt<<<dim3(96, 32), dim3(32, 8), 0, stream>>>(W, Wt);
  k_gemm_qkv<<<dim3(24, 64), dim3(256), 0, stream>>>(Xb, Wt, bias, Qb, Kb, presK, presV);
  k_vt<<<dim3(32, 64), dim3(256), 0, stream>>>(presV, Vt);
  k_flash<<<dim3(64, 8), dim3(512), 0, stream>>>(Qb, Kb, Vt, mask, out);
}

// Round 8
// 298.187 us; speedup vs baseline: 1.0287x; 1.0287x over previous
//
#include <hip/hip_runtime.h>
#include <stdint.h>

// ---------------------------------------------------------------------------
// GPT-2 attention block: qkv = X@W + b; causal MHA; outputs attn_out + present
// B=4 S=2048 D=1024 H=16 Dh=64.  bf16 MFMA path.
// R12: A/B flash v3 — dispatch-independent balance.
//   R10/R11 failed by assuming block->CU placement (undefined per ISA guide).
//   Fix: R8's WITHIN-BLOCK phase pairing (x & 15-x -> 34 tile-iters in every
//   block) + the A/B 32-row wave structure (proven: shared V-frag/amf, spill-
//   free at 76 VGPR).  256-thr blocks (4 waves x 32 rows = 128-row panel),
//   grid (8,64); each wave stages half the K/V tile (2+2 async16, vmcnt(4));
//   LDS 40KB -> 4 blocks/CU (vs R8's 2) for barrier overlap.
// ---------------------------------------------------------------------------

#define B_SZ    4
#define S_LEN   2048
#define D_MODEL 1024
#define N3      3072
#define H_NUM   16
#define DH      64
#define M_TOT   8192   // B*S

typedef __attribute__((ext_vector_type(8))) short short8;   // 8 bf16 (4 VGPRs)
typedef __attribute__((ext_vector_type(4))) short bf16x4;   // 4 bf16 (2 VGPRs)
typedef __attribute__((ext_vector_type(4))) float f32x4;    // MFMA C/D

#define LOG2E      1.4426950408889634f
#define SCL2E      0.18033688011112042f   /* 0.125 * log2(e) */
#define MASKB2     (-14426.9504f)         /* -10000 * log2(e) */

__device__ __forceinline__ unsigned short f2b(float f) {
  union { float f; unsigned int u; } x;
  x.f = f;
  unsigned int u = x.u;
  u += 0x7fffu + ((u >> 16) & 1u);   // round-to-nearest-even
  return (unsigned short)(u >> 16);
}

__device__ __forceinline__ unsigned int cvt_pk_bf16(float lo, float hi) {
  unsigned int r;
  asm("v_cvt_pk_bf16_f32 %0, %1, %2" : "=v"(r) : "v"(lo), "v"(hi));
  return r;
}

__device__ __forceinline__ float exp2_fast(float x) {
#if __has_builtin(__builtin_amdgcn_exp2f)
  return __builtin_amdgcn_exp2f(x);
#else
  return __expf(x * 0.6931471805599453f);
#endif
}

__device__ __forceinline__ f32x4 mfma16(bf16x4 a, bf16x4 b, f32x4 c) {
#if __has_builtin(__builtin_amdgcn_mfma_f32_16x16x16bf16_1k)
  return __builtin_amdgcn_mfma_f32_16x16x16bf16_1k(a, b, c, 0, 0, 0);
#else
  asm("v_mfma_f32_16x16x16_bf16 %0, %1, %2, %0" : "+v"(c) : "v"(a), "v"(b));
  return c;
#endif
}

// async global->LDS, 16B per lane. LDS dest = wave-uniform base + lane*16.
__device__ __forceinline__ void async16(const void* g, void* l) {
  __builtin_amdgcn_global_load_lds((const __attribute__((address_space(1))) void*)g,
                                   (__attribute__((address_space(3))) void*)l,
                                   16, 0, 0);
}

// ---------------- kernel 1: hidden_states fp32 -> bf16 ---------------------
__global__ void k_convert_x(const float* __restrict__ X, unsigned short* __restrict__ Xb) {
  const int i = (blockIdx.x * 256 + threadIdx.x) * 4;
  const float4 v = *(const float4*)(X + i);
  ushort4 o;
  o.x = f2b(v.x); o.y = f2b(v.y); o.z = f2b(v.z); o.w = f2b(v.w);
  *(ushort4*)(Xb + i) = o;
}

// ---------------- kernel 2: W [D,3D] fp32 -> W^T [3D,D] bf16 ----------------
__global__ void k_wt(const float* __restrict__ W, unsigned short* __restrict__ Wt) {
  __shared__ float tile[32][33];
  const int n0 = blockIdx.x * 32, k0 = blockIdx.y * 32;
  const int tx = threadIdx.x, ty = threadIdx.y;   // 32 x 8
  for (int i = 0; i < 32; i += 8)
    tile[ty + i][tx] = W[(size_t)(k0 + ty + i) * N3 + n0 + tx];
  __syncthreads();
  for (int i = 0; i < 32; i += 8)
    Wt[(size_t)(n0 + ty + i) * D_MODEL + k0 + tx] = f2b(tile[tx][ty + i]);
}

// ---------------- kernel 3: QKV GEMM (128x128 tile, BK=32) ------------------
// K-loop: exact R5 structure (m97-class).  Epilogue: per-wave LDS slab
// transpose -> coalesced 128B-row stores for Qb/Kb.
__global__ __launch_bounds__(256) void k_gemm_qkv(
    const unsigned short* __restrict__ Xb, const unsigned short* __restrict__ Wt,
    const float* __restrict__ bias,
    unsigned short* __restrict__ Qb, unsigned short* __restrict__ Kb,
    float* __restrict__ presK, float* __restrict__ presV) {
  __shared__ __align__(16) unsigned short SMEM[8192];   // 16 KB
  unsigned short* As = SMEM;          // [128*32]
  unsigned short* Bs = SMEM + 4096;   // [128*32]
  const int t = threadIdx.x;
  const int lane = t & 63, wave = t >> 6;
  const int g = lane >> 4, c = lane & 15;
  const int m0 = blockIdx.y * 128, n0 = blockIdx.x * 128;
  const int wm = (wave >> 1) * 64, wn = (wave & 1) * 64;

  const f32x4 zero = {0.f, 0.f, 0.f, 0.f};
  f32x4 acc[4][4];
  for (int i = 0; i < 4; ++i)
    for (int j = 0; j < 4; ++j) acc[i][j] = zero;

  const int row_a = t >> 2;          // 0..63
  const int col_a = (t & 3) * 8;     // bf16 elems
  const unsigned short* gA = Xb + (size_t)(m0 + row_a) * D_MODEL + col_a;
  const unsigned short* gB = Wt + (size_t)(n0 + row_a) * D_MODEL + col_a;
  const int wbase = wave * 1024;     // wave-uniform LDS byte base

  for (int k0 = 0; k0 < D_MODEL; k0 += 32) {
    __syncthreads();
    async16(gA + k0,                (char*)As + wbase);
    async16(gA + k0 + 64 * D_MODEL, (char*)As + 4096 + wbase);
    async16(gB + k0,                (char*)Bs + wbase);
    async16(gB + k0 + 64 * D_MODEL, (char*)Bs + 4096 + wbase);
    __syncthreads();

    short8 af[4], bf[4];
    for (int mi = 0; mi < 4; ++mi)
      af[mi] = *(const short8*)(As + (wm + mi * 16 + c) * 32 + g * 8);
    for (int ni = 0; ni < 4; ++ni)
      bf[ni] = *(const short8*)(Bs + (wn + ni * 16 + c) * 32 + g * 8);
    for (int mi = 0; mi < 4; ++mi)
      for (int ni = 0; ni < 4; ++ni)
        acc[mi][ni] = __builtin_amdgcn_mfma_f32_16x16x32_bf16(af[mi], bf[ni], acc[mi][ni], 0, 0, 0);
  }

  __syncthreads();                   // staging LDS reuse as epilogue slab

  // ---- epilogue ----
  // Per wave: one (sec,h); cols = wn + ni*16+c (dh = ni*16+c), rows = wm+mi*16+...
  // C/D layout: col=lane&15 (c), row=(lane>>4)*4+reg (g*4+r).
  const int sec = (n0 + wn) >> 10;            // 0=q 1=k 2=v (wave-uniform)
  const int h = ((n0 + wn) & 1023) >> 6;      // head (wave-uniform)
  unsigned short* slab = SMEM + wave * 1152;  // [16 rows][72 cols] bf16, per-wave
  float bv[4];
  for (int ni = 0; ni < 4; ++ni) bv[ni] = bias[n0 + wn + ni * 16 + c];

  for (int mi = 0; mi < 4; ++mi) {
    const int mrow = m0 + wm + mi * 16;

    if (sec != 2) {
      // bf16 path (Qb / Kb): slab transpose -> 128B coalesced rows
      for (int ni = 0; ni < 4; ++ni)
        for (int r = 0; r < 4; ++r)
          slab[(g * 4 + r) * 72 + ni * 16 + c] = f2b(acc[mi][ni][r] + bv[ni]);
      // same-wave DS ordering; compiler inserts lgkmcnt for the RAW dep
      const short8 w0 = *(const short8*)(slab + c * 72 + g * 16);
      const short8 w1 = *(const short8*)(slab + c * 72 + g * 16 + 8);
      const int srow = mrow + c;
      const int b = srow >> 11, s = srow & 2047;
      unsigned short* dst = (sec == 0 ? Qb : Kb) +
          ((size_t)((b * H_NUM + h) * S_LEN + s)) * DH + g * 16;
      *(short8*)(dst) = w0;
      *(short8*)(dst + 8) = w1;
    }
    if (sec >= 1) {
      // f32 path (presK / presV): direct 64B-segment stores (as R5)
      float* dstf = (sec == 1) ? presK : presV;
      for (int ni = 0; ni < 4; ++ni) {
        const int dh = ni * 16 + c;
        for (int r = 0; r < 4; ++r) {
          const int m = mrow + g * 4 + r;
          const int b = m >> 11, s = m & 2047;
          dstf[((size_t)((b * H_NUM + h) * S_LEN + s)) * DH + dh] =
              acc[mi][ni][r] + bv[ni];
        }
      }
    }
  }
}

// ---------------- kernel 3b: presV fp32 [bh,s,dh] -> Vt bf16 [bh,dh,s] ------
// Vt rows are PERMUTED within each 64-s group: element k stored at position
// p(k) with p[3:2]=k[5:4], p[5:4]=k[3:2], p[1:0]=k[1:0]  (involution), so
// k_flash fetches two ks-fragments per b128.
__global__ __launch_bounds__(256) void k_vt(const float* __restrict__ presV,
                                            unsigned short* __restrict__ Vt) {
  __shared__ unsigned short tile[64 * 72];
  const int t = threadIdx.x;
  const int bh = blockIdx.y;
  const int s0 = blockIdx.x * 64;
  const int row = t >> 2;            // s-row 0..63
  const int dh0 = (t & 3) * 16;
  const float* src = presV + ((size_t)bh * S_LEN + s0 + row) * DH + dh0;
  for (int i = 0; i < 4; ++i) {
    const float4 v = *(const float4*)(src + i * 4);
    const int dh = dh0 + i * 4;
    tile[(dh + 0) * 72 + row] = f2b(v.x);
    tile[(dh + 1) * 72 + row] = f2b(v.y);
    tile[(dh + 2) * 72 + row] = f2b(v.z);
    tile[(dh + 3) * 72 + row] = f2b(v.w);
  }
  __syncthreads();
  const int dh = t >> 2, p0 = (t & 3) * 16;
  unsigned short* dst = Vt + ((size_t)bh * DH + dh) * S_LEN + s0 + p0;
  short8 o0, o1;
  for (int i = 0; i < 8; ++i) {
    const int pa = p0 + i, pb = p0 + 8 + i;
    const int ka = (((pa >> 2) & 3) << 4) | (((pa >> 4) & 3) << 2) | (pa & 3);
    const int kb = (((pb >> 2) & 3) << 4) | (((pb >> 4) & 3) << 2) | (pb & 3);
    o0[i] = (short)tile[dh * 72 + ka];
    o1[i] = (short)tile[dh * 72 + kb];
  }
  *(short8*)(dst) = o0;
  *(short8*)(dst + 8) = o1;
}

// ---------------- kernel 4: causal flash attention --------------------------
// grid (8, 64 bh); 256 thr = 4 waves x 32 q-rows (sets A/B) = 128-row panel;
// phases x and 15-x -> 34 tile-iters in EVERY block (dispatch-independent).
// Each wave stages half the K tile + half the V tile (2+2 async16/tile).
// Sequential per-set QK^T+softmax, SHARED V-frag.  Swapped QK^T, defer-max,
// cvt_pk, b128 V (permuted Vt), counted vmcnt(4) dbuf.  LDS 40KB -> 4 blk/CU.
#define PROC_SET(BQ, QR, NC, MI, LI, OA, PK)                                \
  {                                                                         \
    f32x4 sc[4];                                                            \
    _Pragma("unroll")                                                       \
    for (int ks = 0; ks < 4; ++ks) {                                        \
      f32x4 a = zero;                                                       \
      const int krow = ks * 16 + c;                                         \
      _Pragma("unroll")                                                     \
      for (int kc = 0; kc < 2; ++kc) {                                      \
        const short8 ak = *(const short8*)(ks_base + krow * 64 +            \
                                           (((kc * 4 + g) ^ kslot) * 8));   \
        a = __builtin_amdgcn_mfma_f32_16x16x32_bf16(ak, BQ[kc], a, 0, 0, 0);\
      }                                                                     \
      sc[ks] = a;                                                           \
    }                                                                       \
    float mx = -3.0e38f;                                                    \
    _Pragma("unroll")                                                       \
    for (int ks = 0; ks < 4; ++ks) {                                        \
      _Pragma("unroll")                                                     \
      for (int r = 0; r < 4; ++r) {                                         \
        float v = sc[ks][r] * SCL2E + amf[ks][r];                           \
        if (NC && (kb + ks * 16 + g * 4 + r > (QR))) v = MASKB2 + amf[ks][r];\
        sc[ks][r] = v;                                                      \
      }                                                                     \
      mx = fmaxf(mx, fmaxf(fmaxf(sc[ks][0], sc[ks][1]),                     \
                           fmaxf(sc[ks][2], sc[ks][3])));                   \
    }                                                                       \
    mx = fmaxf(mx, __shfl_xor(mx, 16));                                     \
    mx = fmaxf(mx, __shfl_xor(mx, 32));                                     \
    if (!__all(mx <= MI + 8.0f)) {                                          \
      const float mnew = fmaxf(MI, mx);                                     \
      const float alpha = exp2_fast(MI - mnew);                             \
      MI = mnew;                                                            \
      LI *= alpha;                                                          \
      _Pragma("unroll")                                                     \
      for (int dt = 0; dt < 4; ++dt) OA[dt] *= alpha;                       \
    }                                                                       \
    float rs = 0.f;                                                         \
    _Pragma("unroll")                                                       \
    for (int ks = 0; ks < 4; ++ks) {                                        \
      const float p0 = exp2_fast(sc[ks][0] - MI);                           \
      const float p1 = exp2_fast(sc[ks][1] - MI);                           \
      const float p2 = exp2_fast(sc[ks][2] - MI);                           \
      const float p3 = exp2_fast(sc[ks][3] - MI);                           \
      rs += (p0 + p1) + (p2 + p3);                                          \
      union { unsigned int u[2]; bf16x4 v4; } pu;                           \
      pu.u[0] = cvt_pk_bf16(p0, p1);                                        \
      pu.u[1] = cvt_pk_bf16(p2, p3);                                        \
      PK[ks] = pu.v4;                                                       \
    }                                                                       \
    rs += __shfl_xor(rs, 16);                                               \
    rs += __shfl_xor(rs, 32);                                               \
    LI += rs;                                                               \
  }

__global__ __launch_bounds__(256) void k_flash(
    const unsigned short* __restrict__ Qb, const unsigned short* __restrict__ Kb,
    const unsigned short* __restrict__ Vt, const float* __restrict__ mask,
    float* __restrict__ out) {
  __shared__ __align__(16) unsigned short Ks[2][64 * 64];  // [row][slot] swizzled
  __shared__ __align__(16) unsigned short Vs[2][64 * 64];  // [dh][slot]  swizzled
  __shared__ __align__(16) float Ams[S_LEN];               // (1-mask)*-1e4*log2e
  const int t = threadIdx.x;
  const int lane = t & 63, wave = t >> 6;    // 4 waves
  const int g = lane >> 4, c = lane & 15;
  const int bh = blockIdx.y;
  const int b = bh >> 4, h = bh & 15;
  // staging: thread t -> (row 0..31, swizzled 16B chunk); second async16 does
  // rows 32..63 (same chunk swizzle: (srow+32)&7 == srow&7).  Swizzle folded
  // into the GLOBAL gather address, LDS side stays base+lane*16 (rigid).
  const int srow = t >> 3;                   // 0..31
  const int schunk = (t & 7) ^ (srow & 7);
  const unsigned short* gK0 = Kb + ((size_t)bh * S_LEN + srow) * DH + schunk * 8;
  const unsigned short* gV0 = Vt + ((size_t)bh * DH + srow) * S_LEN + schunk * 8;
  const int kslot = c & 7;                   // frag-read slot xor term

  // exp2-domain additive mask bias, staged once (keeps inner loop VMEM small)
  {
    const float4 mv0 = *(const float4*)(mask + (size_t)b * S_LEN + t * 8);
    const float4 mv1 = *(const float4*)(mask + (size_t)b * S_LEN + t * 8 + 4);
    float4 o0, o1;
    o0.x = (1.0f - mv0.x) * MASKB2; o0.y = (1.0f - mv0.y) * MASKB2;
    o0.z = (1.0f - mv0.z) * MASKB2; o0.w = (1.0f - mv0.w) * MASKB2;
    o1.x = (1.0f - mv1.x) * MASKB2; o1.y = (1.0f - mv1.y) * MASKB2;
    o1.z = (1.0f - mv1.z) * MASKB2; o1.w = (1.0f - mv1.w) * MASKB2;
    *(float4*)(Ams + t * 8) = o0;
    *(float4*)(Ams + t * 8 + 4) = o1;
  }

  const f32x4 zero = {0.f, 0.f, 0.f, 0.f};

  for (int phase = 0; phase < 2; ++phase) {
    const int x = phase ? 15 - (int)blockIdx.x : (int)blockIdx.x;
    const int qb = x * 128;                  // this block's 128-row q panel
    const int qw = qb + wave * 32;           // this wave's 32 q rows (A/B)
    const int qrA = qw + c;                  // lane's q row, set A
    const int qrB = qw + 16 + c;             // lane's q row, set B

    // Q B-frags for both sets (x32 B-layout: n=c, k=g*8+j per 32-wide chunk)
    short8 bqA[2], bqB[2];
    {
      const size_t qoff = ((size_t)bh * S_LEN + qw) * DH;
#pragma unroll
      for (int kc = 0; kc < 2; ++kc) {
        bqA[kc] = *(const short8*)(Qb + qoff + (size_t)c * DH + kc * 32 + g * 8);
        bqB[kc] = *(const short8*)(Qb + qoff + (size_t)(c + 16) * DH + kc * 32 + g * 8);
      }
    }

    float m_iA = -1e30f, l_iA = 0.f, m_iB = -1e30f, l_iB = 0.f;
    f32x4 o_A[4], o_B[4];                    // o[dt][r] = O[q][d=16dt+4g+r]
#pragma unroll
    for (int dt = 0; dt < 4; ++dt) { o_A[dt] = zero; o_B[dt] = zero; }

    const int nt = (qb + 128) >> 6;
    // prologue: stage tile 0 into buffer 0 (4 loads: K lo/hi, V lo/hi)
    async16(gK0,               (char*)(&Ks[0][0]) + wave * 1024);
    async16(gK0 + 32 * DH,     (char*)(&Ks[0][0]) + 4096 + wave * 1024);
    async16(gV0,               (char*)(&Vs[0][0]) + wave * 1024);
    async16(gV0 + 32 * S_LEN,  (char*)(&Vs[0][0]) + 4096 + wave * 1024);

    for (int tt = 0; tt < nt; ++tt) {
      const int kb = tt << 6;
      const int cur = tt & 1;
      if (tt + 1 < nt) {                     // prefetch next tile, keep 4 in flight
        const size_t ko = (size_t)(kb + 64) * DH;
        async16(gK0 + ko,                   (char*)(&Ks[cur ^ 1][0]) + wave * 1024);
        async16(gK0 + ko + 32 * DH,         (char*)(&Ks[cur ^ 1][0]) + 4096 + wave * 1024);
        async16(gV0 + kb + 64,              (char*)(&Vs[cur ^ 1][0]) + wave * 1024);
        async16(gV0 + kb + 64 + 32 * S_LEN, (char*)(&Vs[cur ^ 1][0]) + 4096 + wave * 1024);
        asm volatile("s_waitcnt vmcnt(4) lgkmcnt(0)" ::: "memory");
      } else {
        asm volatile("s_waitcnt vmcnt(0) lgkmcnt(0)" ::: "memory");
      }
      __builtin_amdgcn_s_barrier();          // tile kb fully staged (all waves)
      __builtin_amdgcn_sched_barrier(0);

      // A/B never straddle a 64-tile boundary -> one guard for both sets
      if (qw + 32 > kb) {
        const unsigned short* ks_base = &Ks[cur][0];
        const unsigned short* vs_base = &Vs[cur][0];

        // ---- additive mask (shared by both sets) ----
        float amf[4][4];
#pragma unroll
        for (int ks = 0; ks < 4; ++ks) {
          const float4 amv = *(const float4*)(Ams + kb + ks * 16 + g * 4);
          amf[ks][0] = amv.x; amf[ks][1] = amv.y;
          amf[ks][2] = amv.z; amf[ks][3] = amv.w;
        }
        const bool ncA = (kb + 63 > qw);
        const bool ncB = (kb + 63 > qw + 16);

        // ---- per-set QK^T + softmax + pack, SEQUENTIAL (reg pressure) ----
        bf16x4 pkA[4], pkB[4];
        PROC_SET(bqA, qrA, ncA, m_iA, l_iA, o_A, pkA)
        PROC_SET(bqB, qrB, ncB, m_iB, l_iB, o_B, pkB)

        // ---- O^T += V^T P^T, both sets share the V-frag (8 b128, 32 MFMA) ----
#pragma unroll
        for (int dt = 0; dt < 4; ++dt) {
          const int vrow = dt * 16 + c;
#pragma unroll
          for (int jp = 0; jp < 2; ++jp) {
            union { short8 s8; bf16x4 hh[2]; } vv;
            vv.s8 = *(const short8*)(vs_base + vrow * 64 + (((2 * g + jp) ^ kslot) * 8));
            o_A[dt] = mfma16(vv.hh[0], pkA[2 * jp], o_A[dt]);
            o_A[dt] = mfma16(vv.hh[1], pkA[2 * jp + 1], o_A[dt]);
            o_B[dt] = mfma16(vv.hh[0], pkB[2 * jp], o_B[dt]);
            o_B[dt] = mfma16(vv.hh[1], pkB[2 * jp + 1], o_B[dt]);
          }
        }
      }
      __builtin_amdgcn_sched_barrier(0);
      __builtin_amdgcn_s_barrier();          // all waves done reading buf[cur]
    }

    // ---- normalize + merge heads: O[q][d=16dt+4g+r], float4 stores ----
    {
      const float inv = 1.0f / l_iA;
      float* orow = out + ((size_t)(b * S_LEN + qrA)) * D_MODEL + h * DH;
#pragma unroll
      for (int dt = 0; dt < 4; ++dt) {
        float4 o;
        o.x = o_A[dt][0] * inv;
        o.y = o_A[dt][1] * inv;
        o.z = o_A[dt][2] * inv;
        o.w = o_A[dt][3] * inv;
        *(float4*)(orow + dt * 16 + g * 4) = o;
      }
    }
    {
      const float inv = 1.0f / l_iB;
      float* orow = out + ((size_t)(b * S_LEN + qrB)) * D_MODEL + h * DH;
#pragma unroll
      for (int dt = 0; dt < 4; ++dt) {
        float4 o;
        o.x = o_B[dt][0] * inv;
        o.y = o_B[dt][1] * inv;
        o.z = o_B[dt][2] * inv;
        o.w = o_B[dt][3] * inv;
        *(float4*)(orow + dt * 16 + g * 4) = o;
      }
    }
  }
}

// ---------------------------------------------------------------------------
extern "C" void kernel_launch(void* const* d_in, const int* in_sizes, int n_in,
                              void* d_out, int out_size, void* d_ws, size_t ws_size,
                              hipStream_t stream) {
  const float* X    = (const float*)d_in[0];   // [4,2048,1024]
  const float* mask = (const float*)d_in[1];   // [4,2048]
  const float* W    = (const float*)d_in[2];   // [1024,3072]
  const float* bias = (const float*)d_in[3];   // [3072]

  float* out   = (float*)d_out;                         // attn_output [4,2048,1024]
  float* presK = out + (size_t)M_TOT * D_MODEL;         // present[0]  [4,16,2048,64]
  float* presV = presK + (size_t)M_TOT * D_MODEL;       // present[1]

  char* ws = (char*)d_ws;
  unsigned short* Xb = (unsigned short*)(ws);                    // 16 MB  X bf16 [8192,1024]
  unsigned short* Wt = (unsigned short*)(ws + 16777216);         //  6 MB  W^T bf16 [3072,1024]
  unsigned short* Qb = (unsigned short*)(ws + 23068672);         // 16 MB  Q bf16 [bh,2048,64]
  unsigned short* Kb = (unsigned short*)(ws + 39845888);         // 16 MB  K bf16 [bh,2048,64]
  unsigned short* Vt = (unsigned short*)(ws + 56623104);         // 16 MB  V^T bf16 [bh,64,2048] (row-permuted)

  k_convert_x<<<dim3(8192), dim3(256), 0, stream>>>(X, Xb);
  k_wt<<<dim3(96, 32), dim3(32, 8), 0, stream>>>(W, Wt);
  k_gemm_qkv<<<dim3(24, 64), dim3(256), 0, stream>>>(Xb, Wt, bias, Qb, Kb, presK, presV);
  k_vt<<<dim3(32, 64), dim3(256), 0, stream>>>(presV, Vt);
  k_flash<<<dim3(8, 64), dim3(256), 0, stream>>>(Qb, Kb, Vt, mask, out);
}

// Round 9
// 273.465 us; speedup vs baseline: 1.1217x; 1.0904x over previous
//
#include <hip/hip_runtime.h>
#include <stdint.h>

// ---------------------------------------------------------------------------
// GPT-2 attention block: qkv = X@W + b; causal MHA; outputs attn_out + present
// B=4 S=2048 D=1024 H=16 Dh=64.  bf16 MFMA path.
// R13: consolidation round.
//   * flash: EXACT R8 kernel (90.4us measured; R9-R12 A/B variants all lost).
//   * k_vt DELETED: gemm sec==2 epilogue writes permuted Vt directly.  Lane
//     (c,g) holds V[s=16mi+4g+r][dh=ni*16+c]; the permutation p=16g+4mi+r
//     makes each lane's 16 values CONTIGUOUS -> 8 cvt_pk + 2 b128 stores per
//     ni, no LDS, no shuffle.  Saves the k_vt kernel + one launch gap.
//   * k_convert_x + k_wt merged into one k_prep launch (grid concat).
//   5 launches -> 3.
// ---------------------------------------------------------------------------

#define B_SZ    4
#define S_LEN   2048
#define D_MODEL 1024
#define N3      3072
#define H_NUM   16
#define DH      64
#define M_TOT   8192   // B*S

typedef __attribute__((ext_vector_type(8))) short short8;   // 8 bf16 (4 VGPRs)
typedef __attribute__((ext_vector_type(4))) short bf16x4;   // 4 bf16 (2 VGPRs)
typedef __attribute__((ext_vector_type(4))) float f32x4;    // MFMA C/D

#define LOG2E      1.4426950408889634f
#define SCL2E      0.18033688011112042f   /* 0.125 * log2(e) */
#define MASKB2     (-14426.9504f)         /* -10000 * log2(e) */

__device__ __forceinline__ unsigned short f2b(float f) {
  union { float f; unsigned int u; } x;
  x.f = f;
  unsigned int u = x.u;
  u += 0x7fffu + ((u >> 16) & 1u);   // round-to-nearest-even
  return (unsigned short)(u >> 16);
}

__device__ __forceinline__ unsigned int cvt_pk_bf16(float lo, float hi) {
  unsigned int r;
  asm("v_cvt_pk_bf16_f32 %0, %1, %2" : "=v"(r) : "v"(lo), "v"(hi));
  return r;
}

__device__ __forceinline__ float exp2_fast(float x) {
#if __has_builtin(__builtin_amdgcn_exp2f)
  return __builtin_amdgcn_exp2f(x);
#else
  return __expf(x * 0.6931471805599453f);
#endif
}

__device__ __forceinline__ f32x4 mfma16(bf16x4 a, bf16x4 b, f32x4 c) {
#if __has_builtin(__builtin_amdgcn_mfma_f32_16x16x16bf16_1k)
  return __builtin_amdgcn_mfma_f32_16x16x16bf16_1k(a, b, c, 0, 0, 0);
#else
  asm("v_mfma_f32_16x16x16_bf16 %0, %1, %2, %0" : "+v"(c) : "v"(a), "v"(b));
  return c;
#endif
}

// async global->LDS, 16B per lane. LDS dest = wave-uniform base + lane*16.
__device__ __forceinline__ void async16(const void* g, void* l) {
  __builtin_amdgcn_global_load_lds((const __attribute__((address_space(1))) void*)g,
                                   (__attribute__((address_space(3))) void*)l,
                                   16, 0, 0);
}

// ---------------- kernel 1: prep = convert_x + wt (merged) ------------------
// blocks [0,8192): X fp32 -> Xb bf16.  blocks [8192,11264): W -> W^T bf16.
__global__ __launch_bounds__(256) void k_prep(const float* __restrict__ X,
                                              unsigned short* __restrict__ Xb,
                                              const float* __restrict__ W,
                                              unsigned short* __restrict__ Wt) {
  __shared__ float tile[32][33];
  const int bx = blockIdx.x, t = threadIdx.x;
  if (bx < 8192) {
    const int i = (bx * 256 + t) * 4;
    const float4 v = *(const float4*)(X + i);
    ushort4 o;
    o.x = f2b(v.x); o.y = f2b(v.y); o.z = f2b(v.z); o.w = f2b(v.w);
    *(ushort4*)(Xb + i) = o;
  } else {
    const int idx = bx - 8192;                 // 0..3071
    const int n0 = (idx % 96) * 32, k0 = (idx / 96) * 32;
    const int tx = t & 31, ty = t >> 5;        // 32 x 8
    for (int i = 0; i < 32; i += 8)
      tile[ty + i][tx] = W[(size_t)(k0 + ty + i) * N3 + n0 + tx];
    __syncthreads();
    for (int i = 0; i < 32; i += 8)
      Wt[(size_t)(n0 + ty + i) * D_MODEL + k0 + tx] = f2b(tile[tx][ty + i]);
  }
}

// ---------------- kernel 2: QKV GEMM (128x128 tile, BK=32) ------------------
// K-loop: exact R5 structure (m97-class).  Epilogue: per-wave LDS slab
// transpose -> coalesced 128B-row stores for Qb/Kb; sec==2 writes presV AND
// permuted Vt directly (lane-local contiguity, see header).
__global__ __launch_bounds__(256) void k_gemm_qkv(
    const unsigned short* __restrict__ Xb, const unsigned short* __restrict__ Wt,
    const float* __restrict__ bias,
    unsigned short* __restrict__ Qb, unsigned short* __restrict__ Kb,
    float* __restrict__ presK, float* __restrict__ presV,
    unsigned short* __restrict__ Vt) {
  __shared__ __align__(16) unsigned short SMEM[8192];   // 16 KB
  unsigned short* As = SMEM;          // [128*32]
  unsigned short* Bs = SMEM + 4096;   // [128*32]
  const int t = threadIdx.x;
  const int lane = t & 63, wave = t >> 6;
  const int g = lane >> 4, c = lane & 15;
  const int m0 = blockIdx.y * 128, n0 = blockIdx.x * 128;
  const int wm = (wave >> 1) * 64, wn = (wave & 1) * 64;

  const f32x4 zero = {0.f, 0.f, 0.f, 0.f};
  f32x4 acc[4][4];
  for (int i = 0; i < 4; ++i)
    for (int j = 0; j < 4; ++j) acc[i][j] = zero;

  const int row_a = t >> 2;          // 0..63
  const int col_a = (t & 3) * 8;     // bf16 elems
  const unsigned short* gA = Xb + (size_t)(m0 + row_a) * D_MODEL + col_a;
  const unsigned short* gB = Wt + (size_t)(n0 + row_a) * D_MODEL + col_a;
  const int wbase = wave * 1024;     // wave-uniform LDS byte base

  for (int k0 = 0; k0 < D_MODEL; k0 += 32) {
    __syncthreads();
    async16(gA + k0,                (char*)As + wbase);
    async16(gA + k0 + 64 * D_MODEL, (char*)As + 4096 + wbase);
    async16(gB + k0,                (char*)Bs + wbase);
    async16(gB + k0 + 64 * D_MODEL, (char*)Bs + 4096 + wbase);
    __syncthreads();

    short8 af[4], bf[4];
    for (int mi = 0; mi < 4; ++mi)
      af[mi] = *(const short8*)(As + (wm + mi * 16 + c) * 32 + g * 8);
    for (int ni = 0; ni < 4; ++ni)
      bf[ni] = *(const short8*)(Bs + (wn + ni * 16 + c) * 32 + g * 8);
    for (int mi = 0; mi < 4; ++mi)
      for (int ni = 0; ni < 4; ++ni)
        acc[mi][ni] = __builtin_amdgcn_mfma_f32_16x16x32_bf16(af[mi], bf[ni], acc[mi][ni], 0, 0, 0);
  }

  __syncthreads();                   // staging LDS reuse as epilogue slab

  // ---- epilogue ----
  // C/D layout: col=lane&15 (c), row=(lane>>4)*4+reg (g*4+r).
  const int sec = (n0 + wn) >> 10;            // 0=q 1=k 2=v (wave-uniform)
  const int h = ((n0 + wn) & 1023) >> 6;      // head (wave-uniform)
  unsigned short* slab = SMEM + wave * 1152;  // [16 rows][72 cols] bf16, per-wave
  float bv[4];
  for (int ni = 0; ni < 4; ++ni) bv[ni] = bias[n0 + wn + ni * 16 + c];

  for (int mi = 0; mi < 4; ++mi) {
    const int mrow = m0 + wm + mi * 16;

    if (sec != 2) {
      // bf16 path (Qb / Kb): slab transpose -> 128B coalesced rows
      for (int ni = 0; ni < 4; ++ni)
        for (int r = 0; r < 4; ++r)
          slab[(g * 4 + r) * 72 + ni * 16 + c] = f2b(acc[mi][ni][r] + bv[ni]);
      // same-wave DS ordering; compiler inserts lgkmcnt for the RAW dep
      const short8 w0 = *(const short8*)(slab + c * 72 + g * 16);
      const short8 w1 = *(const short8*)(slab + c * 72 + g * 16 + 8);
      const int srow = mrow + c;
      const int b = srow >> 11, s = srow & 2047;
      unsigned short* dst = (sec == 0 ? Qb : Kb) +
          ((size_t)((b * H_NUM + h) * S_LEN + s)) * DH + g * 16;
      *(short8*)(dst) = w0;
      *(short8*)(dst + 8) = w1;
    }
    if (sec >= 1) {
      // f32 path (presK / presV): direct 64B-segment stores
      float* dstf = (sec == 1) ? presK : presV;
      for (int ni = 0; ni < 4; ++ni) {
        const int dh = ni * 16 + c;
        for (int r = 0; r < 4; ++r) {
          const int m = mrow + g * 4 + r;
          const int b = m >> 11, s = m & 2047;
          dstf[((size_t)((b * H_NUM + h) * S_LEN + s)) * DH + dh] =
              acc[mi][ni][r] + bv[ni];
        }
      }
    }
  }

  if (sec == 2) {
    // Permuted Vt direct write.  Lane (c,g) holds V[s_loc=16mi+4g+r][dh=ni*16+c];
    // permuted position p(s_loc) = 16g + 4mi + r -> each lane's 16 values are
    // CONTIGUOUS at [16g, 16g+16).  8 cvt_pk + 2 b128 stores per ni.
    const int b = (m0 + wm) >> 11, s0 = (m0 + wm) & 2047;
    for (int ni = 0; ni < 4; ++ni) {
      const int dh = ni * 16 + c;
      union { unsigned int u[8]; short8 s8[2]; } pk;
#pragma unroll
      for (int mi = 0; mi < 4; ++mi) {
        pk.u[2 * mi]     = cvt_pk_bf16(acc[mi][ni][0] + bv[ni], acc[mi][ni][1] + bv[ni]);
        pk.u[2 * mi + 1] = cvt_pk_bf16(acc[mi][ni][2] + bv[ni], acc[mi][ni][3] + bv[ni]);
      }
      unsigned short* dst = Vt +
          ((size_t)((b * H_NUM + h)) * DH + dh) * S_LEN + s0 + g * 16;
      *(short8*)(dst) = pk.s8[0];
      *(short8*)(dst + 8) = pk.s8[1];
    }
  }
}

// ---------------- kernel 3: causal flash attention (EXACT R8) ---------------
// grid (8, 64 bh); 512 thr = 8 waves x 16 q-rows; q-tile pair (x, 15-x).
// Swapped QK^T: S^T = mfma(A=K-frag, B=Q-frag) -> lane owns q-row (lane&15),
// 16 k-values in the accumulator. Softmax in-register (2 shfl_xor). P packed
// via v_cvt_pk_bf16_f32 straight into x16-MFMA B-frags; PV as O^T = V^T P^T.
// K/V double-buffered; raw s_barrier + counted vmcnt(2) keeps prefetch alive.
// Defer-max (T13) + b128 V reads from permuted Vt.
__global__ __launch_bounds__(512) void k_flash(
    const unsigned short* __restrict__ Qb, const unsigned short* __restrict__ Kb,
    const unsigned short* __restrict__ Vt, const float* __restrict__ mask,
    float* __restrict__ out) {
  __shared__ __align__(16) unsigned short Ks[2][64 * 64];  // [row][slot] swizzled
  __shared__ __align__(16) unsigned short Vs[2][64 * 64];  // [dh][slot]  swizzled
  __shared__ __align__(16) float Ams[S_LEN];               // (1-mask)*-1e4*log2e
  const int t = threadIdx.x;
  const int lane = t & 63, wave = t >> 6;
  const int g = lane >> 4, c = lane & 15;
  const int bh = blockIdx.y;
  const int b = bh >> 4, h = bh & 15;
  // staging: thread -> (row 0..63, swizzled 16B chunk); swizzle folded into
  // the GLOBAL gather address, LDS side stays base+lane*16 (rigid).
  const int srow = t >> 3;
  const int schunk = (t & 7) ^ (srow & 7);
  const unsigned short* gK0 = Kb + ((size_t)bh * S_LEN + srow) * DH + schunk * 8;
  const unsigned short* gV0 = Vt + ((size_t)bh * DH + srow) * S_LEN + schunk * 8;
  const int kslot = c & 7;                 // frag-read slot xor term

  // exp2-domain additive mask bias, staged once (keeps inner loop VMEM = 2)
  {
    const float4 mv = *(const float4*)(mask + (size_t)b * S_LEN + t * 4);
    float4 o;
    o.x = (1.0f - mv.x) * MASKB2;
    o.y = (1.0f - mv.y) * MASKB2;
    o.z = (1.0f - mv.z) * MASKB2;
    o.w = (1.0f - mv.w) * MASKB2;
    *(float4*)(Ams + t * 4) = o;
  }

  const f32x4 zero = {0.f, 0.f, 0.f, 0.f};

  for (int phase = 0; phase < 2; ++phase) {
    const int x = phase ? 15 - (int)blockIdx.x : (int)blockIdx.x;
    const int qb = x * 128;
    const int qw = qb + wave * 16;         // this wave's 16 q rows
    const int qrow = qw + c;               // this lane's q row

    // Q B-frag (x32 B-layout: n=c, k=g*8+j per 32-wide chunk)
    short8 bq[2];
    const size_t qoff = ((size_t)bh * S_LEN + qw) * DH;
#pragma unroll
    for (int kc = 0; kc < 2; ++kc)
      bq[kc] = *(const short8*)(Qb + qoff + (size_t)c * DH + kc * 32 + g * 8);

    float m_i = -1e30f, l_i = 0.f;
    f32x4 o_acc[4];                        // o_acc[dt][r] = O[q=qrow][d=16dt+4g+r]
#pragma unroll
    for (int dt = 0; dt < 4; ++dt) o_acc[dt] = zero;

    const int nt = (qb + 128) >> 6;
    // prologue: stage tile 0 into buffer 0
    async16(gK0, (char*)(&Ks[0][0]) + wave * 1024);
    async16(gV0, (char*)(&Vs[0][0]) + wave * 1024);

    for (int tt = 0; tt < nt; ++tt) {
      const int kb = tt << 6;
      const int cur = tt & 1;
      if (tt + 1 < nt) {                   // prefetch next tile, keep 2 in flight
        async16(gK0 + (size_t)(kb + 64) * DH, (char*)(&Ks[cur ^ 1][0]) + wave * 1024);
        async16(gV0 + (kb + 64),              (char*)(&Vs[cur ^ 1][0]) + wave * 1024);
        asm volatile("s_waitcnt vmcnt(2) lgkmcnt(0)" ::: "memory");
      } else {
        asm volatile("s_waitcnt vmcnt(0) lgkmcnt(0)" ::: "memory");
      }
      __builtin_amdgcn_s_barrier();        // tile kb fully staged (all waves)
      __builtin_amdgcn_sched_barrier(0);

      if (qw + 16 > kb) {                  // wave has any unmasked row in tile
        const unsigned short* ks_base = &Ks[cur][0];
        const unsigned short* vs_base = &Vs[cur][0];

        // ---- S^T = K Q^T (8 MFMA): sc[ks][r] = S[q=qrow][k=kb+16ks+4g+r] ----
        f32x4 sc[4];
#pragma unroll
        for (int ks = 0; ks < 4; ++ks) {
          f32x4 a = zero;
          const int krow = ks * 16 + c;
#pragma unroll
          for (int kc = 0; kc < 2; ++kc) {
            const short8 ak = *(const short8*)(ks_base + krow * 64 + (((kc * 4 + g) ^ kslot) * 8));
            a = __builtin_amdgcn_mfma_f32_16x16x32_bf16(ak, bq[kc], a, 0, 0, 0);
          }
          sc[ks] = a;
        }

        // ---- scale (exp2 domain), attention mask, causal (diag tiles) ----
        const bool need_causal = (kb + 63 > qw);
        float mxk[4];
#pragma unroll
        for (int ks = 0; ks < 4; ++ks) {
          const float4 amv = *(const float4*)(Ams + kb + ks * 16 + g * 4);
          float am4[4];
          am4[0] = amv.x; am4[1] = amv.y; am4[2] = amv.z; am4[3] = amv.w;
#pragma unroll
          for (int r = 0; r < 4; ++r) {
            float v = sc[ks][r] * SCL2E + am4[r];
            if (need_causal && (kb + ks * 16 + g * 4 + r > qrow))
              v = MASKB2 + am4[r];
            sc[ks][r] = v;
          }
          mxk[ks] = fmaxf(fmaxf(sc[ks][0], sc[ks][1]), fmaxf(sc[ks][2], sc[ks][3]));
        }

        // ---- online softmax: row lives in 4 lanes (same c) ----
        float mx = fmaxf(fmaxf(mxk[0], mxk[1]), fmaxf(mxk[2], mxk[3]));
        mx = fmaxf(mx, __shfl_xor(mx, 16));
        mx = fmaxf(mx, __shfl_xor(mx, 32));
        // T13 defer-max: only rescale when the tile max grew past m_i + 8.
        if (!__all(mx <= m_i + 8.0f)) {
          const float mnew = fmaxf(m_i, mx);
          const float alpha = exp2_fast(m_i - mnew);
          m_i = mnew;
          l_i *= alpha;
#pragma unroll
          for (int dt = 0; dt < 4; ++dt) o_acc[dt] *= alpha;
        }

        bf16x4 pk[4];                      // P B-frags: B[k=4g+j][n=c]
        float rsk[4];
#pragma unroll
        for (int ks = 0; ks < 4; ++ks) {
          const float p0 = exp2_fast(sc[ks][0] - m_i);
          const float p1 = exp2_fast(sc[ks][1] - m_i);
          const float p2 = exp2_fast(sc[ks][2] - m_i);
          const float p3 = exp2_fast(sc[ks][3] - m_i);
          rsk[ks] = (p0 + p1) + (p2 + p3);
          union { unsigned int u[2]; bf16x4 v4; } pu;
          pu.u[0] = cvt_pk_bf16(p0, p1);
          pu.u[1] = cvt_pk_bf16(p2, p3);
          pk[ks] = pu.v4;
        }
        float rs = (rsk[0] + rsk[1]) + (rsk[2] + rsk[3]);
        rs += __shfl_xor(rs, 16);
        rs += __shfl_xor(rs, 32);
        l_i += rs;

        // ---- O^T += V^T P^T (16 x16x16 MFMA; 8 b128 reads, Vt pre-permuted) ----
#pragma unroll
        for (int dt = 0; dt < 4; ++dt) {
          const int vrow = dt * 16 + c;
#pragma unroll
          for (int jp = 0; jp < 2; ++jp) {
            union { short8 s8; bf16x4 hh[2]; } vv;
            vv.s8 = *(const short8*)(vs_base + vrow * 64 + (((2 * g + jp) ^ kslot) * 8));
            o_acc[dt] = mfma16(vv.hh[0], pk[2 * jp], o_acc[dt]);
            o_acc[dt] = mfma16(vv.hh[1], pk[2 * jp + 1], o_acc[dt]);
          }
        }
      }
      __builtin_amdgcn_sched_barrier(0);
      __builtin_amdgcn_s_barrier();        // all waves done reading buf[cur]
    }

    // ---- normalize + merge heads: O[q=qrow][d=16dt+4g+r], float4 stores ----
    const float inv = 1.0f / l_i;
    float* orow = out + ((size_t)(b * S_LEN + qrow)) * D_MODEL + h * DH;
#pragma unroll
    for (int dt = 0; dt < 4; ++dt) {
      float4 o;
      o.x = o_acc[dt][0] * inv;
      o.y = o_acc[dt][1] * inv;
      o.z = o_acc[dt][2] * inv;
      o.w = o_acc[dt][3] * inv;
      *(float4*)(orow + dt * 16 + g * 4) = o;
    }
  }
}

// ---------------------------------------------------------------------------
extern "C" void kernel_launch(void* const* d_in, const int* in_sizes, int n_in,
                              void* d_out, int out_size, void* d_ws, size_t ws_size,
                              hipStream_t stream) {
  const float* X    = (const float*)d_in[0];   // [4,2048,1024]
  const float* mask = (const float*)d_in[1];   // [4,2048]
  const float* W    = (const float*)d_in[2];   // [1024,3072]
  const float* bias = (const float*)d_in[3];   // [3072]

  float* out   = (float*)d_out;                         // attn_output [4,2048,1024]
  float* presK = out + (size_t)M_TOT * D_MODEL;         // present[0]  [4,16,2048,64]
  float* presV = presK + (size_t)M_TOT * D_MODEL;       // present[1]

  char* ws = (char*)d_ws;
  unsigned short* Xb = (unsigned short*)(ws);                    // 16 MB  X bf16 [8192,1024]
  unsigned short* Wt = (unsigned short*)(ws + 16777216);         //  6 MB  W^T bf16 [3072,1024]
  unsigned short* Qb = (unsigned short*)(ws + 23068672);         // 16 MB  Q bf16 [bh,2048,64]
  unsigned short* Kb = (unsigned short*)(ws + 39845888);         // 16 MB  K bf16 [bh,2048,64]
  unsigned short* Vt = (unsigned short*)(ws + 56623104);         // 16 MB  V^T bf16 [bh,64,2048] (row-permuted)

  k_prep<<<dim3(11264), dim3(256), 0, stream>>>(X, Xb, W, Wt);
  k_gemm_qkv<<<dim3(24, 64), dim3(256), 0, stream>>>(Xb, Wt, bias, Qb, Kb, presK, presV, Vt);
  k_flash<<<dim3(8, 64), dim3(512), 0, stream>>>(Qb, Kb, Vt, mask, out);
}